// Round 4
// baseline (1989.237 us; speedup 1.0000x reference)
//
#include <hip/hip_runtime.h>

// GCN_72988674228318: 2-layer GCN on MI355X.
// N=50000 nodes, E=600000 edges, 128 -> 128 -> 64, gcn_norm w/ self-loops,
// ReLU, dropout p=0.5 via Threefry-2x32(key=(0,42)).
// R4: dropout mask uses the **partitionable** threefry path (JAX >= 0.4.36
// default): per-element counter (hi,lo)=(0,i), 32-bit draw = out0 ^ out1,
// keep iff MSB == 0.

#define NN      50000
#define INC     128
#define HIDC    128
#define OUTC    64
#define NE      600000
#define NELEM   6400000   // N*HID

// ---------------- Threefry-2x32, key = (0, 42) (jax.random.key(42)) --------
__device__ __forceinline__ void tf_round(unsigned &x0, unsigned &x1, int r) {
  x0 += x1;
  x1 = (x1 << r) | (x1 >> (32 - r));
  x1 ^= x0;
}

__device__ __forceinline__ void threefry_0_42(unsigned &x0, unsigned &x1) {
  const unsigned ks0 = 0u, ks1 = 42u, ks2 = 0x1BD11BDAu ^ 42u;
  x0 += ks0; x1 += ks1;
  tf_round(x0,x1,13); tf_round(x0,x1,15); tf_round(x0,x1,26); tf_round(x0,x1, 6);
  x0 += ks1; x1 += ks2 + 1u;
  tf_round(x0,x1,17); tf_round(x0,x1,29); tf_round(x0,x1,16); tf_round(x0,x1,24);
  x0 += ks2; x1 += ks0 + 2u;
  tf_round(x0,x1,13); tf_round(x0,x1,15); tf_round(x0,x1,26); tf_round(x0,x1, 6);
  x0 += ks0; x1 += ks1 + 3u;
  tf_round(x0,x1,17); tf_round(x0,x1,29); tf_round(x0,x1,16); tf_round(x0,x1,24);
  x0 += ks1; x1 += ks2 + 4u;
  tf_round(x0,x1,13); tf_round(x0,x1,15); tf_round(x0,x1,26); tf_round(x0,x1, 6);
  x0 += ks2; x1 += ks0 + 5u;
}

// ---------------- edge dtype detect + convert (robustness; int32 in practice)
__global__ void detect_edge_dtype(const unsigned* __restrict__ w, int* __restrict__ flag) {
  __shared__ unsigned acc[256];
  unsigned v = 0;
  for (int i = threadIdx.x; i < 2048; i += 256) v |= w[2 * i + 1];
  acc[threadIdx.x] = v;
  __syncthreads();
  for (int s = 128; s > 0; s >>= 1) {
    if (threadIdx.x < s) acc[threadIdx.x] |= acc[threadIdx.x + s];
    __syncthreads();
  }
  if (threadIdx.x == 0) *flag = (acc[0] == 0u) ? 1 : 0;   // 1 => int64
}

__global__ __launch_bounds__(256)
void convert_edges(const void* __restrict__ ei, const int* __restrict__ flag,
                   int* __restrict__ src, int* __restrict__ dst) {
  int t = blockIdx.x * 256 + threadIdx.x;
  if (t >= NE) return;
  if (*flag) {
    const long long* e = (const long long*)ei;
    src[t] = (int)e[t];
    dst[t] = (int)e[NE + t];
  } else {
    const int* e = (const int*)ei;
    src[t] = e[t];
    dst[t] = e[NE + t];
  }
}

// ---------------- degree ----------------------------------------------------
__global__ void fill_one(float* deg, int n) {
  int t = blockIdx.x * 256 + threadIdx.x;
  if (t < n) deg[t] = 1.0f;   // self-loop contributes 1 to every node
}

__global__ void count_deg(const int* __restrict__ dst, float* deg, int e) {
  int t = blockIdx.x * 256 + threadIdx.x;
  if (t < e) atomicAdd(&deg[dst[t]], 1.0f);
}

__global__ void inv_sqrt(float* deg, int n) {
  int t = blockIdx.x * 256 + threadIdx.x;
  if (t < n) deg[t] = 1.0f / sqrtf(deg[t]);   // deg >= 1 always
}

// ---------------- GEMM: out = (X @ W) * dinv[row], written to A and B -------
template<int K, int C>
__global__ __launch_bounds__(256)
void gemm_scale(const float* __restrict__ X, const float* __restrict__ W,
                const float* __restrict__ dinv,
                float* __restrict__ A, float* __restrict__ B, int n) {
  __shared__ float ws[K * C];
  __shared__ float xs[32 * K];
  const int tid = threadIdx.x;
  const int rowbase = blockIdx.x * 32;

  for (int i = tid * 4; i < K * C; i += 256 * 4)
    *(float4*)&ws[i] = *(const float4*)&W[i];
  for (int i = tid * 4; i < 32 * K; i += 256 * 4) {
    int r = i / K, k = i % K;
    int row = rowbase + r;
    float4 v = make_float4(0.f, 0.f, 0.f, 0.f);
    if (row < n) v = *(const float4*)&X[(size_t)row * K + k];
    *(float4*)&xs[i] = v;
  }
  __syncthreads();

  constexpr int CG  = C / 4;          // col groups of 4
  constexpr int RPT = C / 32;         // rows per thread (128->4, 64->2)
  const int colq = tid % CG;
  const int rowq = tid / CG;

  float acc[RPT][4];
#pragma unroll
  for (int r = 0; r < RPT; r++)
#pragma unroll
    for (int c = 0; c < 4; c++) acc[r][c] = 0.f;

  for (int k0 = 0; k0 < K; k0 += 4) {
    float4 wv[4];
#pragma unroll
    for (int j = 0; j < 4; j++)
      wv[j] = *(float4*)&ws[(k0 + j) * C + colq * 4];
#pragma unroll
    for (int r = 0; r < RPT; r++) {
      float4 xv = *(float4*)&xs[(rowq * RPT + r) * K + k0];
      acc[r][0] += xv.x*wv[0].x + xv.y*wv[1].x + xv.z*wv[2].x + xv.w*wv[3].x;
      acc[r][1] += xv.x*wv[0].y + xv.y*wv[1].y + xv.z*wv[2].y + xv.w*wv[3].y;
      acc[r][2] += xv.x*wv[0].z + xv.y*wv[1].z + xv.z*wv[2].z + xv.w*wv[3].z;
      acc[r][3] += xv.x*wv[0].w + xv.y*wv[1].w + xv.z*wv[2].w + xv.w*wv[3].w;
    }
  }

#pragma unroll
  for (int r = 0; r < RPT; r++) {
    int row = rowbase + rowq * RPT + r;
    if (row < n) {
      float s = dinv[row];
      float4 o = make_float4(acc[r][0]*s, acc[r][1]*s, acc[r][2]*s, acc[r][3]*s);
      *(float4*)&A[(size_t)row * C + colq * 4] = o;
      *(float4*)&B[(size_t)row * C + colq * 4] = o;  // seed B with self-loop term
    }
  }
}

// ---------------- edge scatter: B[dst] += A[src] ----------------------------
template<int C>
__global__ __launch_bounds__(256)
void scatter(const float* __restrict__ A, const int* __restrict__ src,
             const int* __restrict__ dst, float* __restrict__ B, int total) {
  constexpr int G = C / 4;            // float4 groups per row
  int t = blockIdx.x * 256 + threadIdx.x;
  if (t >= total) return;
  int e = t / G;
  int g = t % G;
  int s = src[e], d = dst[e];
  float4 v = *(const float4*)&A[(size_t)s * C + g * 4];
  float* bp = &B[(size_t)d * C + g * 4];
  atomicAdd(bp + 0, v.x);
  atomicAdd(bp + 1, v.y);
  atomicAdd(bp + 2, v.z);
  atomicAdd(bp + 3, v.w);
}

// ---------------- finish layer 1: bias + relu + dropout ---------------------
// Partitionable threefry (JAX >= 0.4.36 default): per-element counter
// (x0,x1) = (hi32(i), lo32(i)) = (0, i); 32-bit draw = out0 ^ out1;
// keep iff MSB(draw) == 0  (uniform < 0.5).
__global__ __launch_bounds__(256)
void finish1(const float* __restrict__ B1, const float* __restrict__ dinv,
             const float* __restrict__ b1, float* __restrict__ hd) {
  int idx = blockIdx.x * 256 + threadIdx.x;
  if (idx >= NELEM) return;
  unsigned x0 = 0u, x1 = (unsigned)idx;
  threefry_0_42(x0, x1);
  int row = idx >> 7, col = idx & 127;
  float v = B1[idx] * dinv[row] + b1[col];
  v = fmaxf(v, 0.f);
  hd[idx] = ((x0 ^ x1) & 0x80000000u) ? 0.f : 2.f * v;
}

// ---------------- finish layer 2: scale + bias -> d_out ---------------------
__global__ __launch_bounds__(256)
void finish2(const float* __restrict__ B2, const float* __restrict__ dinv,
             const float* __restrict__ b2, float* __restrict__ out) {
  int t = blockIdx.x * 256 + threadIdx.x;   // one per float4
  int total = NN * (OUTC / 4);
  if (t >= total) return;
  int row = t >> 4, cg = t & 15;
  float s = dinv[row];
  float4 v = *(const float4*)&B2[(size_t)row * OUTC + cg * 4];
  float4 b = *(const float4*)&b2[cg * 4];
  float4 o = make_float4(v.x*s + b.x, v.y*s + b.y, v.z*s + b.z, v.w*s + b.w);
  *(float4*)&out[(size_t)row * OUTC + cg * 4] = o;
}

// ---------------------------------------------------------------------------
extern "C" void kernel_launch(void* const* d_in, const int* in_sizes, int n_in,
                              void* d_out, int out_size, void* d_ws, size_t ws_size,
                              hipStream_t stream) {
  const float* x  = (const float*)d_in[0];
  const float* W1 = (const float*)d_in[1];
  const float* b1 = (const float*)d_in[2];
  const float* W2 = (const float*)d_in[3];
  const float* b2 = (const float*)d_in[4];
  const void*  ei = d_in[5];                 // [2, E], int32 OR int64
  float* out = (float*)d_out;

  int*   flag = (int*)d_ws;
  int*   src  = flag + 64;
  int*   dst  = src + NE;
  float* dinv = (float*)(dst + NE);
  float* A1   = dinv + 50048;
  float* B1   = A1 + 6400000;
  float* A2   = B1 + 6400000;
  float* B2   = A2 + 3200000;

  // 0. edge dtype detect + convert to int32
  detect_edge_dtype<<<1, 256, 0, stream>>>((const unsigned*)ei, flag);
  convert_edges<<<(NE + 255) / 256, 256, 0, stream>>>(ei, flag, src, dst);

  // 1. degree (self-loop => init 1)
  fill_one<<<(NN + 255) / 256, 256, 0, stream>>>(dinv, NN);
  count_deg<<<(NE + 255) / 256, 256, 0, stream>>>(dst, dinv, NE);
  inv_sqrt<<<(NN + 255) / 256, 256, 0, stream>>>(dinv, NN);

  // 2. layer 1: h1s = (x@W1)*dinv  -> A1, B1
  gemm_scale<INC, HIDC><<<(NN + 31) / 32, 256, 0, stream>>>(x, W1, dinv, A1, B1, NN);

  // 3. scatter: B1[dst] += A1[src]
  scatter<HIDC><<<(NE * (HIDC / 4) + 255) / 256, 256, 0, stream>>>(A1, src, dst, B1, NE * (HIDC / 4));

  // 4. bias + relu + dropout -> hd (reuse A1)
  finish1<<<(NELEM + 255) / 256, 256, 0, stream>>>(B1, dinv, b1, A1);

  // 5. layer 2: h2s = (hd@W2)*dinv -> A2, B2
  gemm_scale<HIDC, OUTC><<<(NN + 31) / 32, 256, 0, stream>>>(A1, W2, dinv, A2, B2, NN);

  // 6. scatter: B2[dst] += A2[src]
  scatter<OUTC><<<(NE * (OUTC / 4) + 255) / 256, 256, 0, stream>>>(A2, src, dst, B2, NE * (OUTC / 4));

  // 7. scale + bias -> out
  finish2<<<(NN * (OUTC / 4) + 255) / 256, 256, 0, stream>>>(B2, dinv, b2, out);
}

// Round 5
// 708.111 us; speedup vs baseline: 2.8092x; 2.8092x over previous
//
#include <hip/hip_runtime.h>

// GCN_72988674228318: 2-layer GCN on MI355X. R5: replace atomic scatter
// (1016+508 us, atomic-throughput-bound) with CSR build + wave-per-node
// gather; fuse bias/relu/dropout into agg1 and bias into agg2.

#define NN      50000
#define INC     128
#define HIDC    128
#define OUTC    64
#define NE      600000

// ---------------- Threefry-2x32, key = (0, 42); partitionable path ---------
__device__ __forceinline__ void tf_round(unsigned &x0, unsigned &x1, int r) {
  x0 += x1;
  x1 = (x1 << r) | (x1 >> (32 - r));
  x1 ^= x0;
}

__device__ __forceinline__ void threefry_0_42(unsigned &x0, unsigned &x1) {
  const unsigned ks0 = 0u, ks1 = 42u, ks2 = 0x1BD11BDAu ^ 42u;
  x0 += ks0; x1 += ks1;
  tf_round(x0,x1,13); tf_round(x0,x1,15); tf_round(x0,x1,26); tf_round(x0,x1, 6);
  x0 += ks1; x1 += ks2 + 1u;
  tf_round(x0,x1,17); tf_round(x0,x1,29); tf_round(x0,x1,16); tf_round(x0,x1,24);
  x0 += ks2; x1 += ks0 + 2u;
  tf_round(x0,x1,13); tf_round(x0,x1,15); tf_round(x0,x1,26); tf_round(x0,x1, 6);
  x0 += ks0; x1 += ks1 + 3u;
  tf_round(x0,x1,17); tf_round(x0,x1,29); tf_round(x0,x1,16); tf_round(x0,x1,24);
  x0 += ks1; x1 += ks2 + 4u;
  tf_round(x0,x1,13); tf_round(x0,x1,15); tf_round(x0,x1,26); tf_round(x0,x1, 6);
  x0 += ks2; x1 += ks0 + 5u;
}

// keep iff MSB(out0 ^ out1) == 0 for counter (0, idx)
__device__ __forceinline__ bool keep_bit(unsigned idx) {
  unsigned x0 = 0u, x1 = idx;
  threefry_0_42(x0, x1);
  return ((x0 ^ x1) & 0x80000000u) == 0u;
}

// ---------------- edge dtype detect + convert -------------------------------
__global__ void detect_edge_dtype(const unsigned* __restrict__ w, int* __restrict__ flag) {
  __shared__ unsigned acc[256];
  unsigned v = 0;
  for (int i = threadIdx.x; i < 2048; i += 256) v |= w[2 * i + 1];
  acc[threadIdx.x] = v;
  __syncthreads();
  for (int s = 128; s > 0; s >>= 1) {
    if (threadIdx.x < s) acc[threadIdx.x] |= acc[threadIdx.x + s];
    __syncthreads();
  }
  if (threadIdx.x == 0) *flag = (acc[0] == 0u) ? 1 : 0;   // 1 => int64
}

__global__ __launch_bounds__(256)
void convert_edges(const void* __restrict__ ei, const int* __restrict__ flag,
                   int* __restrict__ src, int* __restrict__ dst) {
  int t = blockIdx.x * 256 + threadIdx.x;
  if (t >= NE) return;
  if (*flag) {
    const long long* e = (const long long*)ei;
    src[t] = (int)e[t];
    dst[t] = (int)e[NE + t];
  } else {
    const int* e = (const int*)ei;
    src[t] = e[t];
    dst[t] = e[NE + t];
  }
}

// ---------------- CSR build -------------------------------------------------
__global__ void zero_int(int* p, int n) {
  int t = blockIdx.x * 256 + threadIdx.x;
  if (t < n) p[t] = 0;
}

__global__ void count_deg(const int* __restrict__ dst, int* deg, int e) {
  int t = blockIdx.x * 256 + threadIdx.x;
  if (t < e) atomicAdd(&deg[dst[t]], 1);
}

__global__ void calc_dinv(const int* __restrict__ deg, float* __restrict__ dinv, int n) {
  int t = blockIdx.x * 256 + threadIdx.x;
  if (t < n) dinv[t] = 1.0f / sqrtf((float)(deg[t] + 1));   // +1 self-loop
}

// single-block exclusive scan of deg[0..NN) -> offs[0..NN], cursor copy
__global__ __launch_bounds__(256)
void scan_offsets(const int* __restrict__ deg, int* __restrict__ offs,
                  int* __restrict__ cursor) {
  __shared__ int sums[256];
  const int t = threadIdx.x;
  const int CH = (NN + 255) / 256;   // 196
  const int base = t * CH;
  int s = 0;
  for (int i = 0; i < CH; i++) {
    int idx = base + i;
    if (idx < NN) s += deg[idx];
  }
  sums[t] = s;
  __syncthreads();
  for (int off = 1; off < 256; off <<= 1) {
    int v = (t >= off) ? sums[t - off] : 0;
    __syncthreads();
    sums[t] += v;
    __syncthreads();
  }
  int run = (t == 0) ? 0 : sums[t - 1];
  for (int i = 0; i < CH; i++) {
    int idx = base + i;
    if (idx < NN) {
      offs[idx] = run;
      cursor[idx] = run;
      run += deg[idx];
    }
  }
  if (t == 255) offs[NN] = run;   // == NE
}

__global__ __launch_bounds__(256)
void bucket(const int* __restrict__ src, const int* __restrict__ dst,
            int* __restrict__ cursor, int* __restrict__ ssrc) {
  int t = blockIdx.x * 256 + threadIdx.x;
  if (t >= NE) return;
  int pos = atomicAdd(&cursor[dst[t]], 1);
  ssrc[pos] = src[t];
}

// ---------------- GEMM: A = (X @ W) * dinv[row] -----------------------------
template<int K, int C>
__global__ __launch_bounds__(256)
void gemm_scale(const float* __restrict__ X, const float* __restrict__ W,
                const float* __restrict__ dinv, float* __restrict__ A, int n) {
  __shared__ float ws[K * C];
  __shared__ float xs[32 * K];
  const int tid = threadIdx.x;
  const int rowbase = blockIdx.x * 32;

  for (int i = tid * 4; i < K * C; i += 256 * 4)
    *(float4*)&ws[i] = *(const float4*)&W[i];
  for (int i = tid * 4; i < 32 * K; i += 256 * 4) {
    int r = i / K, k = i % K;
    int row = rowbase + r;
    float4 v = make_float4(0.f, 0.f, 0.f, 0.f);
    if (row < n) v = *(const float4*)&X[(size_t)row * K + k];
    *(float4*)&xs[i] = v;
  }
  __syncthreads();

  constexpr int CG  = C / 4;
  constexpr int RPT = C / 32;
  const int colq = tid % CG;
  const int rowq = tid / CG;

  float acc[RPT][4];
#pragma unroll
  for (int r = 0; r < RPT; r++)
#pragma unroll
    for (int c = 0; c < 4; c++) acc[r][c] = 0.f;

  for (int k0 = 0; k0 < K; k0 += 4) {
    float4 wv[4];
#pragma unroll
    for (int j = 0; j < 4; j++)
      wv[j] = *(float4*)&ws[(k0 + j) * C + colq * 4];
#pragma unroll
    for (int r = 0; r < RPT; r++) {
      float4 xv = *(float4*)&xs[(rowq * RPT + r) * K + k0];
      acc[r][0] += xv.x*wv[0].x + xv.y*wv[1].x + xv.z*wv[2].x + xv.w*wv[3].x;
      acc[r][1] += xv.x*wv[0].y + xv.y*wv[1].y + xv.z*wv[2].y + xv.w*wv[3].y;
      acc[r][2] += xv.x*wv[0].z + xv.y*wv[1].z + xv.z*wv[2].z + xv.w*wv[3].z;
      acc[r][3] += xv.x*wv[0].w + xv.y*wv[1].w + xv.z*wv[2].w + xv.w*wv[3].w;
    }
  }

#pragma unroll
  for (int r = 0; r < RPT; r++) {
    int row = rowbase + rowq * RPT + r;
    if (row < n) {
      float s = dinv[row];
      *(float4*)&A[(size_t)row * C + colq * 4] =
        make_float4(acc[r][0]*s, acc[r][1]*s, acc[r][2]*s, acc[r][3]*s);
    }
  }
}

// ---------------- agg1: wave per node, fused bias+relu+dropout --------------
// H[v] = dropout(relu(dinv[v]*(A1[v] + sum_{s in N(v)} A1[s]) + b1))
__global__ __launch_bounds__(256)
void agg1(const float* __restrict__ A1, const int* __restrict__ offs,
          const int* __restrict__ ssrc, const float* __restrict__ dinv,
          const float* __restrict__ b1, float* __restrict__ H) {
  int node = (blockIdx.x * 256 + threadIdx.x) >> 6;
  int lane = threadIdx.x & 63;
  if (node >= NN) return;

  const float2* Av = (const float2*)(A1 + (size_t)node * HIDC);
  float2 acc = Av[lane];                       // self-loop term
  int e = offs[node], end = offs[node + 1];
  for (; e + 1 < end; e += 2) {
    int s0 = ssrc[e], s1 = ssrc[e + 1];
    float2 v0 = ((const float2*)(A1 + (size_t)s0 * HIDC))[lane];
    float2 v1 = ((const float2*)(A1 + (size_t)s1 * HIDC))[lane];
    acc.x += v0.x + v1.x;
    acc.y += v0.y + v1.y;
  }
  if (e < end) {
    float2 v = ((const float2*)(A1 + (size_t)ssrc[e] * HIDC))[lane];
    acc.x += v.x;
    acc.y += v.y;
  }

  float dv = dinv[node];
  int col = lane * 2;
  float h0 = fmaxf(acc.x * dv + b1[col],     0.f);
  float h1 = fmaxf(acc.y * dv + b1[col + 1], 0.f);
  unsigned base = (unsigned)node * HIDC + (unsigned)col;
  float2 o;
  o.x = keep_bit(base)     ? 2.f * h0 : 0.f;
  o.y = keep_bit(base + 1) ? 2.f * h1 : 0.f;
  ((float2*)(H + (size_t)node * HIDC))[lane] = o;
}

// ---------------- agg2: wave per node, fused bias -> d_out ------------------
__global__ __launch_bounds__(256)
void agg2(const float* __restrict__ A2, const int* __restrict__ offs,
          const int* __restrict__ ssrc, const float* __restrict__ dinv,
          const float* __restrict__ b2, float* __restrict__ out) {
  int node = (blockIdx.x * 256 + threadIdx.x) >> 6;
  int lane = threadIdx.x & 63;
  if (node >= NN) return;

  float acc = A2[(size_t)node * OUTC + lane];
  int e = offs[node], end = offs[node + 1];
  for (; e + 1 < end; e += 2) {
    int s0 = ssrc[e], s1 = ssrc[e + 1];
    acc += A2[(size_t)s0 * OUTC + lane] + A2[(size_t)s1 * OUTC + lane];
  }
  if (e < end) acc += A2[(size_t)ssrc[e] * OUTC + lane];

  out[(size_t)node * OUTC + lane] = acc * dinv[node] + b2[lane];
}

// ---------------------------------------------------------------------------
extern "C" void kernel_launch(void* const* d_in, const int* in_sizes, int n_in,
                              void* d_out, int out_size, void* d_ws, size_t ws_size,
                              hipStream_t stream) {
  const float* x  = (const float*)d_in[0];
  const float* W1 = (const float*)d_in[1];
  const float* b1 = (const float*)d_in[2];
  const float* W2 = (const float*)d_in[3];
  const float* b2 = (const float*)d_in[4];
  const void*  ei = d_in[5];
  float* out = (float*)d_out;

  // workspace layout (4-byte units):
  int*   flag   = (int*)d_ws;          // 64
  int*   src    = flag + 64;           // 600000
  int*   dst    = src + NE;            // 600000
  int*   deg    = dst + NE;            // 50048
  int*   offs   = deg + 50048;         // 50056 (NN+1)
  int*   cursor = offs + 50056;        // 50048
  int*   ssrc   = cursor + 50048;      // 600000
  float* dinv   = (float*)(ssrc + NE); // 50048
  float* A1     = dinv + 50048;        // 6.4M
  float* H      = A1 + 6400000;        // 6.4M
  float* A2     = H + 6400000;         // 3.2M   (total ~72 MB)

  // 0. edges -> int32
  detect_edge_dtype<<<1, 256, 0, stream>>>((const unsigned*)ei, flag);
  convert_edges<<<(NE + 255) / 256, 256, 0, stream>>>(ei, flag, src, dst);

  // 1. CSR: degree -> scan -> bucket;  dinv = 1/sqrt(deg+1)
  zero_int<<<(NN + 255) / 256, 256, 0, stream>>>(deg, NN);
  count_deg<<<(NE + 255) / 256, 256, 0, stream>>>(dst, deg, NE);
  calc_dinv<<<(NN + 255) / 256, 256, 0, stream>>>(deg, dinv, NN);
  scan_offsets<<<1, 256, 0, stream>>>(deg, offs, cursor);
  bucket<<<(NE + 255) / 256, 256, 0, stream>>>(src, dst, cursor, ssrc);

  // 2. layer 1
  gemm_scale<INC, HIDC><<<(NN + 31) / 32, 256, 0, stream>>>(x, W1, dinv, A1, NN);
  agg1<<<(NN * 64 + 255) / 256, 256, 0, stream>>>(A1, offs, ssrc, dinv, b1, H);

  // 3. layer 2
  gemm_scale<HIDC, OUTC><<<(NN + 31) / 32, 256, 0, stream>>>(H, W2, dinv, A2, NN);
  agg2<<<(NN * 64 + 255) / 256, 256, 0, stream>>>(A2, offs, ssrc, dinv, b2, out);
}

// Round 6
// 439.290 us; speedup vs baseline: 4.5283x; 1.6119x over previous
//
#include <hip/hip_runtime.h>

// GCN_72988674228318: 2-layer GCN on MI355X. R6: fix the GEMMs —
// R5's gemm_scale allocated 256 VGPRs (spill -> 494 MB HBM writes/dispatch,
// VALUBusy 4.5%, occupancy 10%). Now: __launch_bounds__(256,3) to cap VGPRs,
// and 64-column panels (gridDim.y) so both GEMMs use 48 KB LDS -> 3 blocks/CU.

#define NN      50000
#define INC     128
#define HIDC    128
#define OUTC    64
#define NE      600000

// ---------------- Threefry-2x32, key = (0, 42); partitionable path ---------
__device__ __forceinline__ void tf_round(unsigned &x0, unsigned &x1, int r) {
  x0 += x1;
  x1 = (x1 << r) | (x1 >> (32 - r));
  x1 ^= x0;
}

__device__ __forceinline__ void threefry_0_42(unsigned &x0, unsigned &x1) {
  const unsigned ks0 = 0u, ks1 = 42u, ks2 = 0x1BD11BDAu ^ 42u;
  x0 += ks0; x1 += ks1;
  tf_round(x0,x1,13); tf_round(x0,x1,15); tf_round(x0,x1,26); tf_round(x0,x1, 6);
  x0 += ks1; x1 += ks2 + 1u;
  tf_round(x0,x1,17); tf_round(x0,x1,29); tf_round(x0,x1,16); tf_round(x0,x1,24);
  x0 += ks2; x1 += ks0 + 2u;
  tf_round(x0,x1,13); tf_round(x0,x1,15); tf_round(x0,x1,26); tf_round(x0,x1, 6);
  x0 += ks0; x1 += ks1 + 3u;
  tf_round(x0,x1,17); tf_round(x0,x1,29); tf_round(x0,x1,16); tf_round(x0,x1,24);
  x0 += ks1; x1 += ks2 + 4u;
  tf_round(x0,x1,13); tf_round(x0,x1,15); tf_round(x0,x1,26); tf_round(x0,x1, 6);
  x0 += ks2; x1 += ks0 + 5u;
}

__device__ __forceinline__ bool keep_bit(unsigned idx) {
  unsigned x0 = 0u, x1 = idx;
  threefry_0_42(x0, x1);
  return ((x0 ^ x1) & 0x80000000u) == 0u;
}

// ---------------- edge dtype detect + convert -------------------------------
__global__ void detect_edge_dtype(const unsigned* __restrict__ w, int* __restrict__ flag) {
  __shared__ unsigned acc[256];
  unsigned v = 0;
  for (int i = threadIdx.x; i < 2048; i += 256) v |= w[2 * i + 1];
  acc[threadIdx.x] = v;
  __syncthreads();
  for (int s = 128; s > 0; s >>= 1) {
    if (threadIdx.x < s) acc[threadIdx.x] |= acc[threadIdx.x + s];
    __syncthreads();
  }
  if (threadIdx.x == 0) *flag = (acc[0] == 0u) ? 1 : 0;   // 1 => int64
}

__global__ __launch_bounds__(256)
void convert_edges(const void* __restrict__ ei, const int* __restrict__ flag,
                   int* __restrict__ src, int* __restrict__ dst) {
  int t = blockIdx.x * 256 + threadIdx.x;
  if (t >= NE) return;
  if (*flag) {
    const long long* e = (const long long*)ei;
    src[t] = (int)e[t];
    dst[t] = (int)e[NE + t];
  } else {
    const int* e = (const int*)ei;
    src[t] = e[t];
    dst[t] = e[NE + t];
  }
}

// ---------------- CSR build -------------------------------------------------
__global__ void zero_int(int* p, int n) {
  int t = blockIdx.x * 256 + threadIdx.x;
  if (t < n) p[t] = 0;
}

__global__ void count_deg(const int* __restrict__ dst, int* deg, int e) {
  int t = blockIdx.x * 256 + threadIdx.x;
  if (t < e) atomicAdd(&deg[dst[t]], 1);
}

__global__ void calc_dinv(const int* __restrict__ deg, float* __restrict__ dinv, int n) {
  int t = blockIdx.x * 256 + threadIdx.x;
  if (t < n) dinv[t] = 1.0f / sqrtf((float)(deg[t] + 1));   // +1 self-loop
}

__global__ __launch_bounds__(256)
void scan_offsets(const int* __restrict__ deg, int* __restrict__ offs,
                  int* __restrict__ cursor) {
  __shared__ int sums[256];
  const int t = threadIdx.x;
  const int CH = (NN + 255) / 256;
  const int base = t * CH;
  int s = 0;
  for (int i = 0; i < CH; i++) {
    int idx = base + i;
    if (idx < NN) s += deg[idx];
  }
  sums[t] = s;
  __syncthreads();
  for (int off = 1; off < 256; off <<= 1) {
    int v = (t >= off) ? sums[t - off] : 0;
    __syncthreads();
    sums[t] += v;
    __syncthreads();
  }
  int run = (t == 0) ? 0 : sums[t - 1];
  for (int i = 0; i < CH; i++) {
    int idx = base + i;
    if (idx < NN) {
      offs[idx] = run;
      cursor[idx] = run;
      run += deg[idx];
    }
  }
  if (t == 255) offs[NN] = run;
}

__global__ __launch_bounds__(256)
void bucket(const int* __restrict__ src, const int* __restrict__ dst,
            int* __restrict__ cursor, int* __restrict__ ssrc) {
  int t = blockIdx.x * 256 + threadIdx.x;
  if (t >= NE) return;
  int pos = atomicAdd(&cursor[dst[t]], 1);
  ssrc[pos] = src[t];
}

// ---------------- GEMM: A = (X @ W) * dinv[row], 64-col panels --------------
// grid: (ceil(n/32), C/CT). Block: 256. LDS = K*CT*4 + 32*K*4 = 48 KB (K=128).
// __launch_bounds__(256,3): 3 waves/EU -> VGPR cap ~170, no spill.
template<int K, int C, int CT>
__global__ __launch_bounds__(256, 3)
void gemm_scale(const float* __restrict__ X, const float* __restrict__ W,
                const float* __restrict__ dinv, float* __restrict__ A, int n) {
  __shared__ float ws[K * CT];
  __shared__ float xs[32 * K];
  const int tid = threadIdx.x;
  const int rowbase = blockIdx.x * 32;
  const int c0 = blockIdx.y * CT;

  // stage W panel [K][CT]
  for (int i = tid * 4; i < K * CT; i += 256 * 4) {
    int k = i / CT, c = i % CT;
    *(float4*)&ws[i] = *(const float4*)&W[(size_t)k * C + c0 + c];
  }
  // stage X tile [32][K]
  for (int i = tid * 4; i < 32 * K; i += 256 * 4) {
    int r = i / K, k = i % K;
    int row = rowbase + r;
    float4 v = make_float4(0.f, 0.f, 0.f, 0.f);
    if (row < n) v = *(const float4*)&X[(size_t)row * K + k];
    *(float4*)&xs[i] = v;
  }
  __syncthreads();

  constexpr int CG  = CT / 4;          // 16 col-groups
  constexpr int RPT = 32 * CG / 256;   // rows per thread = 2
  const int colq = tid % CG;
  const int rowq = tid / CG;

  float acc[RPT][4];
#pragma unroll
  for (int r = 0; r < RPT; r++)
#pragma unroll
    for (int c = 0; c < 4; c++) acc[r][c] = 0.f;

#pragma unroll 2
  for (int k0 = 0; k0 < K; k0 += 4) {
    float4 wv[4];
#pragma unroll
    for (int j = 0; j < 4; j++)
      wv[j] = *(float4*)&ws[(k0 + j) * CT + colq * 4];
#pragma unroll
    for (int r = 0; r < RPT; r++) {
      float4 xv = *(float4*)&xs[(rowq * RPT + r) * K + k0];
      acc[r][0] += xv.x*wv[0].x + xv.y*wv[1].x + xv.z*wv[2].x + xv.w*wv[3].x;
      acc[r][1] += xv.x*wv[0].y + xv.y*wv[1].y + xv.z*wv[2].y + xv.w*wv[3].y;
      acc[r][2] += xv.x*wv[0].z + xv.y*wv[1].z + xv.z*wv[2].z + xv.w*wv[3].z;
      acc[r][3] += xv.x*wv[0].w + xv.y*wv[1].w + xv.z*wv[2].w + xv.w*wv[3].w;
    }
  }

#pragma unroll
  for (int r = 0; r < RPT; r++) {
    int row = rowbase + rowq * RPT + r;
    if (row < n) {
      float s = dinv[row];
      *(float4*)&A[(size_t)row * C + c0 + colq * 4] =
        make_float4(acc[r][0]*s, acc[r][1]*s, acc[r][2]*s, acc[r][3]*s);
    }
  }
}

// ---------------- agg1: wave per node, fused bias+relu+dropout --------------
__global__ __launch_bounds__(256)
void agg1(const float* __restrict__ A1, const int* __restrict__ offs,
          const int* __restrict__ ssrc, const float* __restrict__ dinv,
          const float* __restrict__ b1, float* __restrict__ H) {
  int node = (blockIdx.x * 256 + threadIdx.x) >> 6;
  int lane = threadIdx.x & 63;
  if (node >= NN) return;

  const float2* Av = (const float2*)(A1 + (size_t)node * HIDC);
  float2 acc = Av[lane];
  int e = offs[node], end = offs[node + 1];
  for (; e + 1 < end; e += 2) {
    int s0 = ssrc[e], s1 = ssrc[e + 1];
    float2 v0 = ((const float2*)(A1 + (size_t)s0 * HIDC))[lane];
    float2 v1 = ((const float2*)(A1 + (size_t)s1 * HIDC))[lane];
    acc.x += v0.x + v1.x;
    acc.y += v0.y + v1.y;
  }
  if (e < end) {
    float2 v = ((const float2*)(A1 + (size_t)ssrc[e] * HIDC))[lane];
    acc.x += v.x;
    acc.y += v.y;
  }

  float dv = dinv[node];
  int col = lane * 2;
  float h0 = fmaxf(acc.x * dv + b1[col],     0.f);
  float h1 = fmaxf(acc.y * dv + b1[col + 1], 0.f);
  unsigned base = (unsigned)node * HIDC + (unsigned)col;
  float2 o;
  o.x = keep_bit(base)     ? 2.f * h0 : 0.f;
  o.y = keep_bit(base + 1) ? 2.f * h1 : 0.f;
  ((float2*)(H + (size_t)node * HIDC))[lane] = o;
}

// ---------------- agg2: wave per node, fused bias -> d_out ------------------
__global__ __launch_bounds__(256)
void agg2(const float* __restrict__ A2, const int* __restrict__ offs,
          const int* __restrict__ ssrc, const float* __restrict__ dinv,
          const float* __restrict__ b2, float* __restrict__ out) {
  int node = (blockIdx.x * 256 + threadIdx.x) >> 6;
  int lane = threadIdx.x & 63;
  if (node >= NN) return;

  float acc = A2[(size_t)node * OUTC + lane];
  int e = offs[node], end = offs[node + 1];
  for (; e + 1 < end; e += 2) {
    int s0 = ssrc[e], s1 = ssrc[e + 1];
    acc += A2[(size_t)s0 * OUTC + lane] + A2[(size_t)s1 * OUTC + lane];
  }
  if (e < end) acc += A2[(size_t)ssrc[e] * OUTC + lane];

  out[(size_t)node * OUTC + lane] = acc * dinv[node] + b2[lane];
}

// ---------------------------------------------------------------------------
extern "C" void kernel_launch(void* const* d_in, const int* in_sizes, int n_in,
                              void* d_out, int out_size, void* d_ws, size_t ws_size,
                              hipStream_t stream) {
  const float* x  = (const float*)d_in[0];
  const float* W1 = (const float*)d_in[1];
  const float* b1 = (const float*)d_in[2];
  const float* W2 = (const float*)d_in[3];
  const float* b2 = (const float*)d_in[4];
  const void*  ei = d_in[5];
  float* out = (float*)d_out;

  int*   flag   = (int*)d_ws;
  int*   src    = flag + 64;
  int*   dst    = src + NE;
  int*   deg    = dst + NE;
  int*   offs   = deg + 50048;
  int*   cursor = offs + 50056;
  int*   ssrc   = cursor + 50048;
  float* dinv   = (float*)(ssrc + NE);
  float* A1     = dinv + 50048;
  float* H      = A1 + 6400000;
  float* A2     = H + 6400000;

  // 0. edges -> int32
  detect_edge_dtype<<<1, 256, 0, stream>>>((const unsigned*)ei, flag);
  convert_edges<<<(NE + 255) / 256, 256, 0, stream>>>(ei, flag, src, dst);

  // 1. CSR: degree -> scan -> bucket;  dinv = 1/sqrt(deg+1)
  zero_int<<<(NN + 255) / 256, 256, 0, stream>>>(deg, NN);
  count_deg<<<(NE + 255) / 256, 256, 0, stream>>>(dst, deg, NE);
  calc_dinv<<<(NN + 255) / 256, 256, 0, stream>>>(deg, dinv, NN);
  scan_offsets<<<1, 256, 0, stream>>>(deg, offs, cursor);
  bucket<<<(NE + 255) / 256, 256, 0, stream>>>(src, dst, cursor, ssrc);

  // 2. layer 1 (two 64-col panels)
  gemm_scale<INC, HIDC, 64><<<dim3((NN + 31) / 32, HIDC / 64), 256, 0, stream>>>(x, W1, dinv, A1, NN);
  agg1<<<(NN * 64 + 255) / 256, 256, 0, stream>>>(A1, offs, ssrc, dinv, b1, H);

  // 3. layer 2 (one 64-col panel)
  gemm_scale<HIDC, OUTC, 64><<<dim3((NN + 31) / 32, 1), 256, 0, stream>>>(H, W2, dinv, A2, NN);
  agg2<<<(NN * 64 + 255) / 256, 256, 0, stream>>>(A2, offs, ssrc, dinv, b2, out);
}

// Round 7
// 307.882 us; speedup vs baseline: 6.4610x; 1.4268x over previous
//
#include <hip/hip_runtime.h>

// GCN_72988674228318: 2-layer GCN on MI355X. R7: kill the 138 us single-block
// scan_offsets (1 CU, 0.045% occupancy) -> 3-stage hierarchical scan across
// the chip; fuse degree-count into convert_edges and dinv into scan_a.

#define NN      50000
#define INC     128
#define HIDC    128
#define OUTC    64
#define NE      600000
#define NB      ((NN + 255) / 256)   // 196 scan blocks

// ---------------- Threefry-2x32, key = (0, 42); partitionable path ---------
__device__ __forceinline__ void tf_round(unsigned &x0, unsigned &x1, int r) {
  x0 += x1;
  x1 = (x1 << r) | (x1 >> (32 - r));
  x1 ^= x0;
}

__device__ __forceinline__ void threefry_0_42(unsigned &x0, unsigned &x1) {
  const unsigned ks0 = 0u, ks1 = 42u, ks2 = 0x1BD11BDAu ^ 42u;
  x0 += ks0; x1 += ks1;
  tf_round(x0,x1,13); tf_round(x0,x1,15); tf_round(x0,x1,26); tf_round(x0,x1, 6);
  x0 += ks1; x1 += ks2 + 1u;
  tf_round(x0,x1,17); tf_round(x0,x1,29); tf_round(x0,x1,16); tf_round(x0,x1,24);
  x0 += ks2; x1 += ks0 + 2u;
  tf_round(x0,x1,13); tf_round(x0,x1,15); tf_round(x0,x1,26); tf_round(x0,x1, 6);
  x0 += ks0; x1 += ks1 + 3u;
  tf_round(x0,x1,17); tf_round(x0,x1,29); tf_round(x0,x1,16); tf_round(x0,x1,24);
  x0 += ks1; x1 += ks2 + 4u;
  tf_round(x0,x1,13); tf_round(x0,x1,15); tf_round(x0,x1,26); tf_round(x0,x1, 6);
  x0 += ks2; x1 += ks0 + 5u;
}

__device__ __forceinline__ bool keep_bit(unsigned idx) {
  unsigned x0 = 0u, x1 = idx;
  threefry_0_42(x0, x1);
  return ((x0 ^ x1) & 0x80000000u) == 0u;
}

// ---------------- edge dtype detect -----------------------------------------
__global__ void detect_edge_dtype(const unsigned* __restrict__ w, int* __restrict__ flag) {
  __shared__ unsigned acc[256];
  unsigned v = 0;
  for (int i = threadIdx.x; i < 2048; i += 256) v |= w[2 * i + 1];
  acc[threadIdx.x] = v;
  __syncthreads();
  for (int s = 128; s > 0; s >>= 1) {
    if (threadIdx.x < s) acc[threadIdx.x] |= acc[threadIdx.x + s];
    __syncthreads();
  }
  if (threadIdx.x == 0) *flag = (acc[0] == 0u) ? 1 : 0;   // 1 => int64
}

__global__ void zero_int(int* p, int n) {
  int t = blockIdx.x * 256 + threadIdx.x;
  if (t < n) p[t] = 0;
}

// convert to int32 AND count in-degree (fused)
__global__ __launch_bounds__(256)
void convert_edges(const void* __restrict__ ei, const int* __restrict__ flag,
                   int* __restrict__ src, int* __restrict__ dst,
                   int* __restrict__ deg) {
  int t = blockIdx.x * 256 + threadIdx.x;
  if (t >= NE) return;
  int s, d;
  if (*flag) {
    const long long* e = (const long long*)ei;
    s = (int)e[t];
    d = (int)e[NE + t];
  } else {
    const int* e = (const int*)ei;
    s = e[t];
    d = e[NE + t];
  }
  src[t] = s;
  dst[t] = d;
  atomicAdd(&deg[d], 1);
}

// ---------------- hierarchical scan of deg -> offs/cursor -------------------
// stage a: per-block sum of 256 deg entries -> bsum; fused dinv = rsqrt(deg+1)
__global__ __launch_bounds__(256)
void scan_a(const int* __restrict__ deg, int* __restrict__ bsum,
            float* __restrict__ dinv) {
  __shared__ int red[256];
  int t = threadIdx.x, idx = blockIdx.x * 256 + t;
  int d = (idx < NN) ? deg[idx] : 0;
  if (idx < NN) dinv[idx] = 1.0f / sqrtf((float)(d + 1));
  red[t] = d;
  __syncthreads();
  for (int s = 128; s > 0; s >>= 1) {
    if (t < s) red[t] += red[t + s];
    __syncthreads();
  }
  if (t == 0) bsum[blockIdx.x] = red[0];
}

// stage b: single small block scans the NB block sums -> boff (exclusive)
__global__ __launch_bounds__(256)
void scan_b(const int* __restrict__ bsum, int* __restrict__ boff,
            int* __restrict__ offs) {
  __shared__ int sums[256];
  int t = threadIdx.x;
  int v = (t < NB) ? bsum[t] : 0;
  sums[t] = v;
  __syncthreads();
  for (int off = 1; off < 256; off <<= 1) {
    int u = (t >= off) ? sums[t - off] : 0;
    __syncthreads();
    sums[t] += u;
    __syncthreads();
  }
  if (t < NB) boff[t] = sums[t] - v;   // exclusive
  if (t == 255) offs[NN] = sums[255];  // total == NE
}

// stage c: block-local exclusive scan + block offset -> offs, cursor
__global__ __launch_bounds__(256)
void scan_c(const int* __restrict__ deg, const int* __restrict__ boff,
            int* __restrict__ offs, int* __restrict__ cursor) {
  __shared__ int sums[256];
  int t = threadIdx.x, idx = blockIdx.x * 256 + t;
  int d = (idx < NN) ? deg[idx] : 0;
  sums[t] = d;
  __syncthreads();
  for (int off = 1; off < 256; off <<= 1) {
    int u = (t >= off) ? sums[t - off] : 0;
    __syncthreads();
    sums[t] += u;
    __syncthreads();
  }
  if (idx < NN) {
    int o = boff[blockIdx.x] + sums[t] - d;
    offs[idx] = o;
    cursor[idx] = o;
  }
}

__global__ __launch_bounds__(256)
void bucket(const int* __restrict__ src, const int* __restrict__ dst,
            int* __restrict__ cursor, int* __restrict__ ssrc) {
  int t = blockIdx.x * 256 + threadIdx.x;
  if (t >= NE) return;
  int pos = atomicAdd(&cursor[dst[t]], 1);
  ssrc[pos] = src[t];
}

// ---------------- GEMM: A = (X @ W) * dinv[row], 64-col panels --------------
template<int K, int C, int CT>
__global__ __launch_bounds__(256, 3)
void gemm_scale(const float* __restrict__ X, const float* __restrict__ W,
                const float* __restrict__ dinv, float* __restrict__ A, int n) {
  __shared__ float ws[K * CT];
  __shared__ float xs[32 * K];
  const int tid = threadIdx.x;
  const int rowbase = blockIdx.x * 32;
  const int c0 = blockIdx.y * CT;

  for (int i = tid * 4; i < K * CT; i += 256 * 4) {
    int k = i / CT, c = i % CT;
    *(float4*)&ws[i] = *(const float4*)&W[(size_t)k * C + c0 + c];
  }
  for (int i = tid * 4; i < 32 * K; i += 256 * 4) {
    int r = i / K, k = i % K;
    int row = rowbase + r;
    float4 v = make_float4(0.f, 0.f, 0.f, 0.f);
    if (row < n) v = *(const float4*)&X[(size_t)row * K + k];
    *(float4*)&xs[i] = v;
  }
  __syncthreads();

  constexpr int CG  = CT / 4;
  constexpr int RPT = 32 * CG / 256;
  const int colq = tid % CG;
  const int rowq = tid / CG;

  float acc[RPT][4];
#pragma unroll
  for (int r = 0; r < RPT; r++)
#pragma unroll
    for (int c = 0; c < 4; c++) acc[r][c] = 0.f;

#pragma unroll 2
  for (int k0 = 0; k0 < K; k0 += 4) {
    float4 wv[4];
#pragma unroll
    for (int j = 0; j < 4; j++)
      wv[j] = *(float4*)&ws[(k0 + j) * CT + colq * 4];
#pragma unroll
    for (int r = 0; r < RPT; r++) {
      float4 xv = *(float4*)&xs[(rowq * RPT + r) * K + k0];
      acc[r][0] += xv.x*wv[0].x + xv.y*wv[1].x + xv.z*wv[2].x + xv.w*wv[3].x;
      acc[r][1] += xv.x*wv[0].y + xv.y*wv[1].y + xv.z*wv[2].y + xv.w*wv[3].y;
      acc[r][2] += xv.x*wv[0].z + xv.y*wv[1].z + xv.z*wv[2].z + xv.w*wv[3].z;
      acc[r][3] += xv.x*wv[0].w + xv.y*wv[1].w + xv.z*wv[2].w + xv.w*wv[3].w;
    }
  }

#pragma unroll
  for (int r = 0; r < RPT; r++) {
    int row = rowbase + rowq * RPT + r;
    if (row < n) {
      float s = dinv[row];
      *(float4*)&A[(size_t)row * C + c0 + colq * 4] =
        make_float4(acc[r][0]*s, acc[r][1]*s, acc[r][2]*s, acc[r][3]*s);
    }
  }
}

// ---------------- agg1: wave per node, fused bias+relu+dropout --------------
__global__ __launch_bounds__(256)
void agg1(const float* __restrict__ A1, const int* __restrict__ offs,
          const int* __restrict__ ssrc, const float* __restrict__ dinv,
          const float* __restrict__ b1, float* __restrict__ H) {
  int node = (blockIdx.x * 256 + threadIdx.x) >> 6;
  int lane = threadIdx.x & 63;
  if (node >= NN) return;

  const float2* Av = (const float2*)(A1 + (size_t)node * HIDC);
  float2 acc = Av[lane];
  int e = offs[node], end = offs[node + 1];
  for (; e + 1 < end; e += 2) {
    int s0 = ssrc[e], s1 = ssrc[e + 1];
    float2 v0 = ((const float2*)(A1 + (size_t)s0 * HIDC))[lane];
    float2 v1 = ((const float2*)(A1 + (size_t)s1 * HIDC))[lane];
    acc.x += v0.x + v1.x;
    acc.y += v0.y + v1.y;
  }
  if (e < end) {
    float2 v = ((const float2*)(A1 + (size_t)ssrc[e] * HIDC))[lane];
    acc.x += v.x;
    acc.y += v.y;
  }

  float dv = dinv[node];
  int col = lane * 2;
  float h0 = fmaxf(acc.x * dv + b1[col],     0.f);
  float h1 = fmaxf(acc.y * dv + b1[col + 1], 0.f);
  unsigned base = (unsigned)node * HIDC + (unsigned)col;
  float2 o;
  o.x = keep_bit(base)     ? 2.f * h0 : 0.f;
  o.y = keep_bit(base + 1) ? 2.f * h1 : 0.f;
  ((float2*)(H + (size_t)node * HIDC))[lane] = o;
}

// ---------------- agg2: wave per node, fused bias -> d_out ------------------
__global__ __launch_bounds__(256)
void agg2(const float* __restrict__ A2, const int* __restrict__ offs,
          const int* __restrict__ ssrc, const float* __restrict__ dinv,
          const float* __restrict__ b2, float* __restrict__ out) {
  int node = (blockIdx.x * 256 + threadIdx.x) >> 6;
  int lane = threadIdx.x & 63;
  if (node >= NN) return;

  float acc = A2[(size_t)node * OUTC + lane];
  int e = offs[node], end = offs[node + 1];
  for (; e + 1 < end; e += 2) {
    int s0 = ssrc[e], s1 = ssrc[e + 1];
    acc += A2[(size_t)s0 * OUTC + lane] + A2[(size_t)s1 * OUTC + lane];
  }
  if (e < end) acc += A2[(size_t)ssrc[e] * OUTC + lane];

  out[(size_t)node * OUTC + lane] = acc * dinv[node] + b2[lane];
}

// ---------------------------------------------------------------------------
extern "C" void kernel_launch(void* const* d_in, const int* in_sizes, int n_in,
                              void* d_out, int out_size, void* d_ws, size_t ws_size,
                              hipStream_t stream) {
  const float* x  = (const float*)d_in[0];
  const float* W1 = (const float*)d_in[1];
  const float* b1 = (const float*)d_in[2];
  const float* W2 = (const float*)d_in[3];
  const float* b2 = (const float*)d_in[4];
  const void*  ei = d_in[5];
  float* out = (float*)d_out;

  int*   flag   = (int*)d_ws;          // 64
  int*   src    = flag + 64;           // 600000
  int*   dst    = src + NE;            // 600000
  int*   deg    = dst + NE;            // 50048
  int*   offs   = deg + 50048;         // 50056
  int*   cursor = offs + 50056;        // 50048
  int*   ssrc   = cursor + 50048;      // 600000
  int*   bsum   = ssrc + NE;           // 256
  int*   boff   = bsum + 256;          // 256
  float* dinv   = (float*)(boff + 256);// 50048
  float* A1     = dinv + 50048;        // 6.4M
  float* H      = A1 + 6400000;        // 6.4M
  float* A2     = H + 6400000;         // 3.2M

  // 0. edges -> int32 (+ degree count fused)
  detect_edge_dtype<<<1, 256, 0, stream>>>((const unsigned*)ei, flag);
  zero_int<<<(NN + 255) / 256, 256, 0, stream>>>(deg, NN);
  convert_edges<<<(NE + 255) / 256, 256, 0, stream>>>(ei, flag, src, dst, deg);

  // 1. hierarchical scan -> offs/cursor (+ dinv fused into stage a)
  scan_a<<<NB, 256, 0, stream>>>(deg, bsum, dinv);
  scan_b<<<1, 256, 0, stream>>>(bsum, boff, offs);
  scan_c<<<NB, 256, 0, stream>>>(deg, boff, offs, cursor);
  bucket<<<(NE + 255) / 256, 256, 0, stream>>>(src, dst, cursor, ssrc);

  // 2. layer 1 (two 64-col panels)
  gemm_scale<INC, HIDC, 64><<<dim3((NN + 31) / 32, HIDC / 64), 256, 0, stream>>>(x, W1, dinv, A1, NN);
  agg1<<<(NN * 64 + 255) / 256, 256, 0, stream>>>(A1, offs, ssrc, dinv, b1, H);

  // 3. layer 2 (one 64-col panel)
  gemm_scale<HIDC, OUTC, 64><<<dim3((NN + 31) / 32, 1), 256, 0, stream>>>(H, W2, dinv, A2, NN);
  agg2<<<(NN * 64 + 255) / 256, 256, 0, stream>>>(A2, offs, ssrc, dinv, b2, out);
}

// Round 8
// 290.748 us; speedup vs baseline: 6.8418x; 1.0589x over previous
//
#include <hip/hip_runtime.h>

// GCN_72988674228318: 2-layer GCN on MI355X. R8: agg kernels reshaped for
// memory-level parallelism — half-wave/node + float4 in agg1 (1 instr / 2
// edges), quarter-wave/node + float4 in agg2 (1 instr / 4 edges), unroll 4.

#define NN      50000
#define INC     128
#define HIDC    128
#define OUTC    64
#define NE      600000
#define NB      ((NN + 255) / 256)   // 196 scan blocks

// ---------------- Threefry-2x32, key = (0, 42); partitionable path ---------
__device__ __forceinline__ void tf_round(unsigned &x0, unsigned &x1, int r) {
  x0 += x1;
  x1 = (x1 << r) | (x1 >> (32 - r));
  x1 ^= x0;
}

__device__ __forceinline__ void threefry_0_42(unsigned &x0, unsigned &x1) {
  const unsigned ks0 = 0u, ks1 = 42u, ks2 = 0x1BD11BDAu ^ 42u;
  x0 += ks0; x1 += ks1;
  tf_round(x0,x1,13); tf_round(x0,x1,15); tf_round(x0,x1,26); tf_round(x0,x1, 6);
  x0 += ks1; x1 += ks2 + 1u;
  tf_round(x0,x1,17); tf_round(x0,x1,29); tf_round(x0,x1,16); tf_round(x0,x1,24);
  x0 += ks2; x1 += ks0 + 2u;
  tf_round(x0,x1,13); tf_round(x0,x1,15); tf_round(x0,x1,26); tf_round(x0,x1, 6);
  x0 += ks0; x1 += ks1 + 3u;
  tf_round(x0,x1,17); tf_round(x0,x1,29); tf_round(x0,x1,16); tf_round(x0,x1,24);
  x0 += ks1; x1 += ks2 + 4u;
  tf_round(x0,x1,13); tf_round(x0,x1,15); tf_round(x0,x1,26); tf_round(x0,x1, 6);
  x0 += ks2; x1 += ks0 + 5u;
}

__device__ __forceinline__ bool keep_bit(unsigned idx) {
  unsigned x0 = 0u, x1 = idx;
  threefry_0_42(x0, x1);
  return ((x0 ^ x1) & 0x80000000u) == 0u;
}

// ---------------- edge dtype detect -----------------------------------------
__global__ void detect_edge_dtype(const unsigned* __restrict__ w, int* __restrict__ flag) {
  __shared__ unsigned acc[256];
  unsigned v = 0;
  for (int i = threadIdx.x; i < 2048; i += 256) v |= w[2 * i + 1];
  acc[threadIdx.x] = v;
  __syncthreads();
  for (int s = 128; s > 0; s >>= 1) {
    if (threadIdx.x < s) acc[threadIdx.x] |= acc[threadIdx.x + s];
    __syncthreads();
  }
  if (threadIdx.x == 0) *flag = (acc[0] == 0u) ? 1 : 0;   // 1 => int64
}

__global__ void zero_int(int* p, int n) {
  int t = blockIdx.x * 256 + threadIdx.x;
  if (t < n) p[t] = 0;
}

// convert to int32 AND count in-degree (fused)
__global__ __launch_bounds__(256)
void convert_edges(const void* __restrict__ ei, const int* __restrict__ flag,
                   int* __restrict__ src, int* __restrict__ dst,
                   int* __restrict__ deg) {
  int t = blockIdx.x * 256 + threadIdx.x;
  if (t >= NE) return;
  int s, d;
  if (*flag) {
    const long long* e = (const long long*)ei;
    s = (int)e[t];
    d = (int)e[NE + t];
  } else {
    const int* e = (const int*)ei;
    s = e[t];
    d = e[NE + t];
  }
  src[t] = s;
  dst[t] = d;
  atomicAdd(&deg[d], 1);
}

// ---------------- hierarchical scan of deg -> offs/cursor -------------------
__global__ __launch_bounds__(256)
void scan_a(const int* __restrict__ deg, int* __restrict__ bsum,
            float* __restrict__ dinv) {
  __shared__ int red[256];
  int t = threadIdx.x, idx = blockIdx.x * 256 + t;
  int d = (idx < NN) ? deg[idx] : 0;
  if (idx < NN) dinv[idx] = 1.0f / sqrtf((float)(d + 1));
  red[t] = d;
  __syncthreads();
  for (int s = 128; s > 0; s >>= 1) {
    if (t < s) red[t] += red[t + s];
    __syncthreads();
  }
  if (t == 0) bsum[blockIdx.x] = red[0];
}

__global__ __launch_bounds__(256)
void scan_b(const int* __restrict__ bsum, int* __restrict__ boff,
            int* __restrict__ offs) {
  __shared__ int sums[256];
  int t = threadIdx.x;
  int v = (t < NB) ? bsum[t] : 0;
  sums[t] = v;
  __syncthreads();
  for (int off = 1; off < 256; off <<= 1) {
    int u = (t >= off) ? sums[t - off] : 0;
    __syncthreads();
    sums[t] += u;
    __syncthreads();
  }
  if (t < NB) boff[t] = sums[t] - v;
  if (t == 255) offs[NN] = sums[255];
}

__global__ __launch_bounds__(256)
void scan_c(const int* __restrict__ deg, const int* __restrict__ boff,
            int* __restrict__ offs, int* __restrict__ cursor) {
  __shared__ int sums[256];
  int t = threadIdx.x, idx = blockIdx.x * 256 + t;
  int d = (idx < NN) ? deg[idx] : 0;
  sums[t] = d;
  __syncthreads();
  for (int off = 1; off < 256; off <<= 1) {
    int u = (t >= off) ? sums[t - off] : 0;
    __syncthreads();
    sums[t] += u;
    __syncthreads();
  }
  if (idx < NN) {
    int o = boff[blockIdx.x] + sums[t] - d;
    offs[idx] = o;
    cursor[idx] = o;
  }
}

__global__ __launch_bounds__(256)
void bucket(const int* __restrict__ src, const int* __restrict__ dst,
            int* __restrict__ cursor, int* __restrict__ ssrc) {
  int t = blockIdx.x * 256 + threadIdx.x;
  if (t >= NE) return;
  int pos = atomicAdd(&cursor[dst[t]], 1);
  ssrc[pos] = src[t];
}

// ---------------- GEMM: A = (X @ W) * dinv[row], 64-col panels --------------
template<int K, int C, int CT>
__global__ __launch_bounds__(256, 3)
void gemm_scale(const float* __restrict__ X, const float* __restrict__ W,
                const float* __restrict__ dinv, float* __restrict__ A, int n) {
  __shared__ float ws[K * CT];
  __shared__ float xs[32 * K];
  const int tid = threadIdx.x;
  const int rowbase = blockIdx.x * 32;
  const int c0 = blockIdx.y * CT;

  for (int i = tid * 4; i < K * CT; i += 256 * 4) {
    int k = i / CT, c = i % CT;
    *(float4*)&ws[i] = *(const float4*)&W[(size_t)k * C + c0 + c];
  }
  for (int i = tid * 4; i < 32 * K; i += 256 * 4) {
    int r = i / K, k = i % K;
    int row = rowbase + r;
    float4 v = make_float4(0.f, 0.f, 0.f, 0.f);
    if (row < n) v = *(const float4*)&X[(size_t)row * K + k];
    *(float4*)&xs[i] = v;
  }
  __syncthreads();

  constexpr int CG  = CT / 4;
  constexpr int RPT = 32 * CG / 256;
  const int colq = tid % CG;
  const int rowq = tid / CG;

  float acc[RPT][4];
#pragma unroll
  for (int r = 0; r < RPT; r++)
#pragma unroll
    for (int c = 0; c < 4; c++) acc[r][c] = 0.f;

#pragma unroll 2
  for (int k0 = 0; k0 < K; k0 += 4) {
    float4 wv[4];
#pragma unroll
    for (int j = 0; j < 4; j++)
      wv[j] = *(float4*)&ws[(k0 + j) * CT + colq * 4];
#pragma unroll
    for (int r = 0; r < RPT; r++) {
      float4 xv = *(float4*)&xs[(rowq * RPT + r) * K + k0];
      acc[r][0] += xv.x*wv[0].x + xv.y*wv[1].x + xv.z*wv[2].x + xv.w*wv[3].x;
      acc[r][1] += xv.x*wv[0].y + xv.y*wv[1].y + xv.z*wv[2].y + xv.w*wv[3].y;
      acc[r][2] += xv.x*wv[0].z + xv.y*wv[1].z + xv.z*wv[2].z + xv.w*wv[3].z;
      acc[r][3] += xv.x*wv[0].w + xv.y*wv[1].w + xv.z*wv[2].w + xv.w*wv[3].w;
    }
  }

#pragma unroll
  for (int r = 0; r < RPT; r++) {
    int row = rowbase + rowq * RPT + r;
    if (row < n) {
      float s = dinv[row];
      *(float4*)&A[(size_t)row * C + c0 + colq * 4] =
        make_float4(acc[r][0]*s, acc[r][1]*s, acc[r][2]*s, acc[r][3]*s);
    }
  }
}

__device__ __forceinline__ void f4add(float4 &a, const float4 &b) {
  a.x += b.x; a.y += b.y; a.z += b.z; a.w += b.w;
}

// ---------------- agg1: half-wave (32 lanes) per node, float4/lane ----------
// H[v] = dropout(relu(dinv[v]*(A1[v] + sum_{s in N(v)} A1[s]) + b1))
__global__ __launch_bounds__(256)
void agg1(const float* __restrict__ A1, const int* __restrict__ offs,
          const int* __restrict__ ssrc, const float* __restrict__ dinv,
          const float* __restrict__ b1, float* __restrict__ H) {
  int node = (blockIdx.x * 256 + threadIdx.x) >> 5;   // half-wave id
  int lane = threadIdx.x & 31;                         // col group 0..31
  if (node >= NN) return;

  float4 acc = ((const float4*)(A1 + (size_t)node * HIDC))[lane];  // self-loop
  int e = offs[node], end = offs[node + 1];
  for (; e + 3 < end; e += 4) {
    int s0 = ssrc[e], s1 = ssrc[e + 1], s2 = ssrc[e + 2], s3 = ssrc[e + 3];
    float4 v0 = ((const float4*)(A1 + (size_t)s0 * HIDC))[lane];
    float4 v1 = ((const float4*)(A1 + (size_t)s1 * HIDC))[lane];
    float4 v2 = ((const float4*)(A1 + (size_t)s2 * HIDC))[lane];
    float4 v3 = ((const float4*)(A1 + (size_t)s3 * HIDC))[lane];
    f4add(v0, v1); f4add(v2, v3); f4add(v0, v2); f4add(acc, v0);
  }
  for (; e < end; e++) {
    float4 v = ((const float4*)(A1 + (size_t)ssrc[e] * HIDC))[lane];
    f4add(acc, v);
  }

  float dv = dinv[node];
  int col = lane * 4;
  float4 bb = *(const float4*)&b1[col];
  float h0 = fmaxf(acc.x * dv + bb.x, 0.f);
  float h1 = fmaxf(acc.y * dv + bb.y, 0.f);
  float h2 = fmaxf(acc.z * dv + bb.z, 0.f);
  float h3 = fmaxf(acc.w * dv + bb.w, 0.f);
  unsigned base = (unsigned)node * HIDC + (unsigned)col;
  float4 o;
  o.x = keep_bit(base)     ? 2.f * h0 : 0.f;
  o.y = keep_bit(base + 1) ? 2.f * h1 : 0.f;
  o.z = keep_bit(base + 2) ? 2.f * h2 : 0.f;
  o.w = keep_bit(base + 3) ? 2.f * h3 : 0.f;
  ((float4*)(H + (size_t)node * HIDC))[lane] = o;
}

// ---------------- agg2: quarter-wave (16 lanes) per node, float4/lane -------
__global__ __launch_bounds__(256)
void agg2(const float* __restrict__ A2, const int* __restrict__ offs,
          const int* __restrict__ ssrc, const float* __restrict__ dinv,
          const float* __restrict__ b2, float* __restrict__ out) {
  int node = (blockIdx.x * 256 + threadIdx.x) >> 4;   // quarter-wave id
  int lane = threadIdx.x & 15;                         // col group 0..15
  if (node >= NN) return;

  float4 acc = ((const float4*)(A2 + (size_t)node * OUTC))[lane];
  int e = offs[node], end = offs[node + 1];
  for (; e + 3 < end; e += 4) {
    int s0 = ssrc[e], s1 = ssrc[e + 1], s2 = ssrc[e + 2], s3 = ssrc[e + 3];
    float4 v0 = ((const float4*)(A2 + (size_t)s0 * OUTC))[lane];
    float4 v1 = ((const float4*)(A2 + (size_t)s1 * OUTC))[lane];
    float4 v2 = ((const float4*)(A2 + (size_t)s2 * OUTC))[lane];
    float4 v3 = ((const float4*)(A2 + (size_t)s3 * OUTC))[lane];
    f4add(v0, v1); f4add(v2, v3); f4add(v0, v2); f4add(acc, v0);
  }
  for (; e < end; e++) {
    float4 v = ((const float4*)(A2 + (size_t)ssrc[e] * OUTC))[lane];
    f4add(acc, v);
  }

  float dv = dinv[node];
  float4 bb = *(const float4*)&b2[lane * 4];
  float4 o = make_float4(acc.x * dv + bb.x, acc.y * dv + bb.y,
                         acc.z * dv + bb.z, acc.w * dv + bb.w);
  ((float4*)(out + (size_t)node * OUTC))[lane] = o;
}

// ---------------------------------------------------------------------------
extern "C" void kernel_launch(void* const* d_in, const int* in_sizes, int n_in,
                              void* d_out, int out_size, void* d_ws, size_t ws_size,
                              hipStream_t stream) {
  const float* x  = (const float*)d_in[0];
  const float* W1 = (const float*)d_in[1];
  const float* b1 = (const float*)d_in[2];
  const float* W2 = (const float*)d_in[3];
  const float* b2 = (const float*)d_in[4];
  const void*  ei = d_in[5];
  float* out = (float*)d_out;

  int*   flag   = (int*)d_ws;          // 64
  int*   src    = flag + 64;           // 600000
  int*   dst    = src + NE;            // 600000
  int*   deg    = dst + NE;            // 50048
  int*   offs   = deg + 50048;         // 50056
  int*   cursor = offs + 50056;        // 50048
  int*   ssrc   = cursor + 50048;      // 600000
  int*   bsum   = ssrc + NE;           // 256
  int*   boff   = bsum + 256;          // 256
  float* dinv   = (float*)(boff + 256);// 50048
  float* A1     = dinv + 50048;        // 6.4M
  float* H      = A1 + 6400000;        // 6.4M
  float* A2     = H + 6400000;         // 3.2M

  // 0. edges -> int32 (+ degree count fused)
  detect_edge_dtype<<<1, 256, 0, stream>>>((const unsigned*)ei, flag);
  zero_int<<<(NN + 255) / 256, 256, 0, stream>>>(deg, NN);
  convert_edges<<<(NE + 255) / 256, 256, 0, stream>>>(ei, flag, src, dst, deg);

  // 1. hierarchical scan -> offs/cursor (+ dinv fused into stage a)
  scan_a<<<NB, 256, 0, stream>>>(deg, bsum, dinv);
  scan_b<<<1, 256, 0, stream>>>(bsum, boff, offs);
  scan_c<<<NB, 256, 0, stream>>>(deg, boff, offs, cursor);
  bucket<<<(NE + 255) / 256, 256, 0, stream>>>(src, dst, cursor, ssrc);

  // 2. layer 1 (two 64-col panels); agg1: 8 nodes per 256-thread block
  gemm_scale<INC, HIDC, 64><<<dim3((NN + 31) / 32, HIDC / 64), 256, 0, stream>>>(x, W1, dinv, A1, NN);
  agg1<<<(NN * 32 + 255) / 256, 256, 0, stream>>>(A1, offs, ssrc, dinv, b1, H);

  // 3. layer 2 (one 64-col panel); agg2: 16 nodes per block
  gemm_scale<HIDC, OUTC, 64><<<dim3((NN + 31) / 32, 1), 256, 0, stream>>>(H, W2, dinv, A2, NN);
  agg2<<<(NN * 16 + 255) / 256, 256, 0, stream>>>(A2, offs, ssrc, dinv, b2, out);
}